// Round 8
// baseline (335.741 us; speedup 1.0000x reference)
//
#include <hip/hip_runtime.h>
#include <math.h>

#define HH 12
#define NN 1024

typedef unsigned int u32;
typedef unsigned short u16;
typedef __attribute__((ext_vector_type(8))) short bf16x8;
typedef __attribute__((ext_vector_type(4))) float f32x4;
typedef __attribute__((ext_vector_type(4))) unsigned short u16x4;

#define QSCALE 0.18033688f   // 0.125 * log2(e): folded scale + base-2 softmax

__device__ __forceinline__ u16 bf16_rtn(float f) {
    u32 u = __builtin_bit_cast(u32, f);
    return (u16)((u + 0x7FFFu + ((u >> 16) & 1u)) >> 16);
}
__device__ __forceinline__ float bf16_up(u16 h) {
    u32 u = ((u32)h) << 16;
    return __builtin_bit_cast(float, u);
}
// async global->LDS, 16B per lane, dest = uniform base + lane*16
__device__ __forceinline__ void gld_lds16(const void* g, void* l) {
    __builtin_amdgcn_global_load_lds(
        (const __attribute__((address_space(1))) u32*)(unsigned long long)g,
        (__attribute__((address_space(3))) u32*)(u32)(unsigned long long)l,
        16, 0, 0);
}

// ---------------------------------------------------------------------------
// One-time f32 -> (hi,lo) bf16 split, rtn both planes (err ~2^-18)
// ---------------------------------------------------------------------------
__global__ __launch_bounds__(256) void presplit(const float* __restrict__ in,
                                                u16* __restrict__ hi, u16* __restrict__ lo,
                                                int n4) {
    int i = blockIdx.x * 256 + threadIdx.x;
    if (i >= n4) return;
    float4 v = ((const float4*)in)[i];
    float f[4] = {v.x, v.y, v.z, v.w};
    u16x4 h, l;
#pragma unroll
    for (int j = 0; j < 4; ++j) {
        u16 hh = bf16_rtn(f[j]);
        h[j] = hh;
        l[j] = bf16_rtn(f[j] - bf16_up(hh));
    }
    ((u16x4*)hi)[i] = h;
    ((u16x4*)lo)[i] = l;
}

// ---------------------------------------------------------------------------
// QKV GEMM (unchanged from round 7, control): 128x64 tile, single-buffer,
// all-async staging, grid 1152, XCD-chunked swizzle.
// ---------------------------------------------------------------------------
__global__ __launch_bounds__(256) void gemm_qkv(const u16* __restrict__ Xh,
                                                const u16* __restrict__ Xl,
                                                const u16* __restrict__ Wh,
                                                const u16* __restrict__ Wl,
                                                u16* __restrict__ qh, u16* __restrict__ ql,
                                                u16* __restrict__ kh, u16* __restrict__ kl,
                                                u16* __restrict__ vT) {
    __shared__ __align__(16) u16 sA[2][8][512];   // [pl][tile][lane*8] 16KB
    __shared__ __align__(16) u16 sB[2][4][512];   // [pl][tile][lane*8]  8KB

    const int tid = threadIdx.x, wave = tid >> 6, lane = tid & 63;
    const int g = lane >> 4, c = lane & 15;
    const int bid = blockIdx.x;
    const int T = (bid & 7) * 144 + (bid >> 3);
    const int m0 = (T / 36) * 128, c0 = (T % 36) * 64;
    const int wm = wave >> 1, wn = wave & 1;

    f32x4 acc[4][2];
#pragma unroll
    for (int i = 0; i < 4; ++i)
#pragma unroll
        for (int j = 0; j < 2; ++j) acc[i][j] = (f32x4)(0.f);

    for (int kt = 0; kt < 24; ++kt) {
        __syncthreads();
#pragma unroll
        for (int qq = 0; qq < 6; ++qq) {
            const int idx = wave * 6 + qq;
            if (idx < 16) {
                const int pl = idx >> 3, t = idx & 7;
                const u16* src = (pl ? Xl : Xh) + (size_t)(m0 + t * 16 + c) * 768 + kt * 32 + g * 8;
                gld_lds16(src, &sA[pl][t][0]);
            } else {
                const int rem = idx - 16, pl = rem >> 2, t = rem & 3;
                const u16* src = (pl ? Wl : Wh) + (size_t)(c0 + t * 16 + c) * 768 + kt * 32 + g * 8;
                gld_lds16(src, &sB[pl][t][0]);
            }
        }
        __syncthreads();

        bf16x8 Ah[4], Al[4], Bh[2], Bl[2];
#pragma unroll
        for (int i = 0; i < 4; ++i) {
            Ah[i] = *(const bf16x8*)&sA[0][wm * 4 + i][lane * 8];
            Al[i] = *(const bf16x8*)&sA[1][wm * 4 + i][lane * 8];
        }
#pragma unroll
        for (int j = 0; j < 2; ++j) {
            Bh[j] = *(const bf16x8*)&sB[0][wn * 2 + j][lane * 8];
            Bl[j] = *(const bf16x8*)&sB[1][wn * 2 + j][lane * 8];
        }
#pragma unroll
        for (int i = 0; i < 4; ++i)
#pragma unroll
            for (int j = 0; j < 2; ++j) {
                acc[i][j] = __builtin_amdgcn_mfma_f32_16x16x32_bf16(Ah[i], Bh[j], acc[i][j], 0, 0, 0);
                acc[i][j] = __builtin_amdgcn_mfma_f32_16x16x32_bf16(Ah[i], Bl[j], acc[i][j], 0, 0, 0);
                acc[i][j] = __builtin_amdgcn_mfma_f32_16x16x32_bf16(Al[i], Bh[j], acc[i][j], 0, 0, 0);
            }
    }

    const int b = m0 >> 10;
#pragma unroll
    for (int j = 0; j < 2; ++j) {
        const int cg = c0 + wn * 32 + j * 16;
        const int s = cg / 768;
        const int h = (cg % 768) / 64;
        const int d = (cg % 64) + c;
#pragma unroll
        for (int i = 0; i < 4; ++i) {
            const int nbase = (m0 & 1023) + wm * 64 + i * 16 + g * 4;
            if (s == 2) {
                u16x4 pk;
#pragma unroll
                for (int r = 0; r < 4; ++r) pk[r] = bf16_rtn(acc[i][j][r]);
                *(u16x4*)(vT + ((size_t)(b * HH + h) << 16) + (size_t)d * 1024 + nbase) = pk;
            } else {
                u16* dh = s ? kh : qh;
                u16* dl = s ? kl : ql;
                const float sc = s ? 1.0f : QSCALE;
#pragma unroll
                for (int r = 0; r < 4; ++r) {
                    const float vv = acc[i][j][r] * sc;
                    const u16 hh = bf16_rtn(vv);
                    const size_t a = ((size_t)(b * HH + h) * NN + nbase + r) * 64 + d;
                    dh[a] = hh;
                    dl[a] = bf16_rtn(vv - bf16_up(hh));
                }
            }
        }
    }
}

// ---------------------------------------------------------------------------
// Flash attention, MFMA, barrier-free, direct K/V loads from L2.
// ROUND 8: wave = 16 q-rows (was 32), block = 4 waves = 64 rows ->
// grid 768 = 3 blocks/CU = 12 waves/CU (was 384 = 1.5 blocks/CU).
// V fragments prefetched into registers at tile start (latency hides
// under QK^T + softmax). bh-major: all 16 blocks of one bh on one XCD.
// ---------------------------------------------------------------------------
__global__ __launch_bounds__(256) void attn_mfma(const u16* __restrict__ qh_,
                                                 const u16* __restrict__ ql_,
                                                 const u16* __restrict__ kh_,
                                                 const u16* __restrict__ kl_,
                                                 const u16* __restrict__ vT,
                                                 const float* __restrict__ rel_table,
                                                 u16* __restrict__ attout) {
    __shared__ __align__(16) u16 sP[4][16][72];     // per-wave P (9KB)
    __shared__ float tbl[132];

    const int tid = threadIdx.x, wave = tid >> 6, lane = tid & 63;
    const int g = lane >> 4, c = lane & 15;
    const int bh = blockIdx.x % 48;                 // 48*16 grid; same-bh -> same XCD
    const int q0 = (blockIdx.x / 48) * 64;
    const int b = bh / HH, h = bh % HH;
    const int qrow0 = q0 + wave * 16;

    if (tid < 129) tbl[tid] = rel_table[tid * HH + h] * 1.44269504f;

    // hoist Q fragments (16 rows per wave)
    bf16x8 Qh[2], Ql[2];
#pragma unroll
    for (int ks = 0; ks < 2; ++ks) {
        const size_t a = ((size_t)bh * NN + qrow0 + c) * 64 + ks * 32 + g * 8;
        Qh[ks] = *(const bf16x8*)(qh_ + a);
        Ql[ks] = *(const bf16x8*)(ql_ + a);
    }

    // lane-fixed base pointers for direct K/V fragment loads
    const u16* kbh = kh_ + ((size_t)bh * NN + c) * 64 + g * 8;
    const u16* kbl = kl_ + ((size_t)bh * NN + c) * 64 + g * 8;
    const u16* vb = vT + ((size_t)bh << 16) + (size_t)c * 1024 + g * 8;

    f32x4 O[4];
    float mrun[4], lrun[4];
#pragma unroll
    for (int r = 0; r < 4; ++r) {
        mrun[r] = -INFINITY;
        lrun[r] = 0.f;
    }
#pragma unroll
    for (int dj = 0; dj < 4; ++dj) O[dj] = (f32x4)(0.f);

    __syncthreads();  // tbl visible (only barrier in the kernel)

    for (int t = 0; t < 16; ++t) {
        const int kv0 = t * 64;

        // prefetch V fragments for this tile (independent of QK chain)
        bf16x8 Vf[2][4];
#pragma unroll
        for (int ks = 0; ks < 2; ++ks)
#pragma unroll
            for (int dj = 0; dj < 4; ++dj)
                Vf[ks][dj] = *(const bf16x8*)(vb + (size_t)(dj * 16) * 1024 + kv0 + ks * 32);

        // S = QK^T (3-term split), K fragments direct from global (L2)
        f32x4 S[4];
#pragma unroll
        for (int jn = 0; jn < 4; ++jn) S[jn] = (f32x4)(0.f);
#pragma unroll
        for (int jn = 0; jn < 4; ++jn) {
#pragma unroll
            for (int ks = 0; ks < 2; ++ks) {
                const size_t off = (size_t)(kv0 + jn * 16) * 64 + ks * 32;
                const bf16x8 Kh_ = *(const bf16x8*)(kbh + off);
                const bf16x8 Kl_ = *(const bf16x8*)(kbl + off);
                __builtin_amdgcn_s_setprio(1);
                S[jn] = __builtin_amdgcn_mfma_f32_16x16x32_bf16(Qh[ks], Kh_, S[jn], 0, 0, 0);
                S[jn] = __builtin_amdgcn_mfma_f32_16x16x32_bf16(Qh[ks], Kl_, S[jn], 0, 0, 0);
                S[jn] = __builtin_amdgcn_mfma_f32_16x16x32_bf16(Ql[ks], Kh_, S[jn], 0, 0, 0);
                __builtin_amdgcn_s_setprio(0);
            }
        }

        // + relative-position bias (log2 domain); wave-uniform clamp fast path
#pragma unroll
        for (int jn = 0; jn < 4; ++jn) {
            const int dd = (kv0 + jn * 16) - qrow0;
            if (dd <= -79) {
                const float bv = tbl[0];
#pragma unroll
                for (int r = 0; r < 4; ++r) S[jn][r] += bv;
            } else if (dd >= 79) {
                const float bv = tbl[128];
#pragma unroll
                for (int r = 0; r < 4; ++r) S[jn][r] += bv;
            } else {
#pragma unroll
                for (int r = 0; r < 4; ++r) {
                    int off = dd + c - g * 4 - r + 64;
                    off = off < 0 ? 0 : (off > 128 ? 128 : off);
                    S[jn][r] += tbl[off];
                }
            }
        }

        // online softmax (base 2); rows live on 16-lane c-groups
#pragma unroll
        for (int r = 0; r < 4; ++r) {
            float mx = fmaxf(fmaxf(S[0][r], S[1][r]), fmaxf(S[2][r], S[3][r]));
            mx = fmaxf(mx, __shfl_xor(mx, 1));
            mx = fmaxf(mx, __shfl_xor(mx, 2));
            mx = fmaxf(mx, __shfl_xor(mx, 4));
            mx = fmaxf(mx, __shfl_xor(mx, 8));
            const float mnew = fmaxf(mrun[r], mx);
            const float alpha = exp2f(mrun[r] - mnew);
            mrun[r] = mnew;
            float rs = 0.f;
#pragma unroll
            for (int jn = 0; jn < 4; ++jn) {
                const float p = exp2f(S[jn][r] - mnew);
                S[jn][r] = p;
                rs += p;
            }
            rs += __shfl_xor(rs, 1);
            rs += __shfl_xor(rs, 2);
            rs += __shfl_xor(rs, 4);
            rs += __shfl_xor(rs, 8);
            lrun[r] = lrun[r] * alpha + rs;
#pragma unroll
            for (int dj = 0; dj < 4; ++dj) O[dj][r] *= alpha;
        }

        // P -> bf16, transpose through per-wave LDS (wave-coherent, no barrier)
#pragma unroll
        for (int jn = 0; jn < 4; ++jn)
#pragma unroll
            for (int r = 0; r < 4; ++r)
                sP[wave][g * 4 + r][jn * 16 + c] = bf16_rtn(S[jn][r]);

        // O += P V (V already in registers)
#pragma unroll
        for (int ks = 0; ks < 2; ++ks) {
            const bf16x8 Pa = *(const bf16x8*)&sP[wave][c][ks * 32 + g * 8];
            __builtin_amdgcn_s_setprio(1);
#pragma unroll
            for (int dj = 0; dj < 4; ++dj)
                O[dj] = __builtin_amdgcn_mfma_f32_16x16x32_bf16(Pa, Vf[ks][dj], O[dj], 0, 0, 0);
            __builtin_amdgcn_s_setprio(0);
        }
    }

    // epilogue: normalize, write attout bf16 [b][n][768]
#pragma unroll
    for (int r = 0; r < 4; ++r) {
        const float inv = 1.0f / lrun[r];
        const int n = qrow0 + g * 4 + r;
        u16* dst = attout + (size_t)(b * NN + n) * 768 + h * 64;
#pragma unroll
        for (int dj = 0; dj < 4; ++dj)
            dst[dj * 16 + c] = bf16_rtn(O[dj][r] * inv);
    }
}

// ---------------------------------------------------------------------------
// Proj GEMM (unchanged from round 7, control): 64x64 tile, single-buffer,
// async staging, grid 768, XCD-chunked swizzle.
// ---------------------------------------------------------------------------
__global__ __launch_bounds__(256) void gemm_proj(const u16* __restrict__ A,
                                                 const u16* __restrict__ Wh,
                                                 const u16* __restrict__ Wl,
                                                 const float* __restrict__ bias,
                                                 float* __restrict__ out) {
    __shared__ __align__(16) u16 sA[4][512];      // [tile][lane*8]  4KB
    __shared__ __align__(16) u16 sB[2][4][512];   // [pl][tile][lane*8] 8KB

    const int tid = threadIdx.x, wave = tid >> 6, lane = tid & 63;
    const int g = lane >> 4, c = lane & 15;
    const int bid = blockIdx.x;
    const int T = (bid & 7) * 96 + (bid >> 3);
    const int m0 = (T / 12) * 64, c0 = (T % 12) * 64;
    const int wm = wave >> 1, wn = wave & 1;

    f32x4 acc[2][2];
#pragma unroll
    for (int i = 0; i < 2; ++i)
#pragma unroll
        for (int j = 0; j < 2; ++j) acc[i][j] = (f32x4)(0.f);

    for (int kt = 0; kt < 24; ++kt) {
        __syncthreads();
#pragma unroll
        for (int qq = 0; qq < 3; ++qq) {
            const int idx = wave * 3 + qq;
            if (idx < 4) {
                const u16* src = A + (size_t)(m0 + idx * 16 + c) * 768 + kt * 32 + g * 8;
                gld_lds16(src, &sA[idx][0]);
            } else {
                const int rem = idx - 4, pl = rem >> 2, t = rem & 3;
                const u16* src = (pl ? Wl : Wh) + (size_t)(c0 + t * 16 + c) * 768 + kt * 32 + g * 8;
                gld_lds16(src, &sB[pl][t][0]);
            }
        }
        __syncthreads();

        bf16x8 Aa[2], Bh[2], Bl[2];
#pragma unroll
        for (int i = 0; i < 2; ++i) {
            Aa[i] = *(const bf16x8*)&sA[wm * 2 + i][lane * 8];
            Bh[i] = *(const bf16x8*)&sB[0][wn * 2 + i][lane * 8];
            Bl[i] = *(const bf16x8*)&sB[1][wn * 2 + i][lane * 8];
        }
#pragma unroll
        for (int i = 0; i < 2; ++i)
#pragma unroll
            for (int j = 0; j < 2; ++j) {
                acc[i][j] = __builtin_amdgcn_mfma_f32_16x16x32_bf16(Aa[i], Bh[j], acc[i][j], 0, 0, 0);
                acc[i][j] = __builtin_amdgcn_mfma_f32_16x16x32_bf16(Aa[i], Bl[j], acc[i][j], 0, 0, 0);
            }
    }

#pragma unroll
    for (int j = 0; j < 2; ++j) {
        const int cg = c0 + wn * 32 + j * 16 + c;
        const float bv = bias[cg];
#pragma unroll
        for (int i = 0; i < 2; ++i)
#pragma unroll
            for (int r = 0; r < 4; ++r) {
                const int m = m0 + wm * 32 + i * 16 + g * 4 + r;
                out[(size_t)m * 768 + cg] = acc[i][j][r] + bv;
            }
    }
}

// ---------------------------------------------------------------------------
extern "C" void kernel_launch(void* const* d_in, const int* in_sizes, int n_in,
                              void* d_out, int out_size, void* d_ws, size_t ws_size,
                              hipStream_t stream) {
    const float* x = (const float*)d_in[0];
    const float* qkv_w = (const float*)d_in[1];
    const float* proj_w = (const float*)d_in[2];
    const float* proj_b = (const float*)d_in[3];
    const float* rel_table = (const float*)d_in[4];

    char* ws = (char*)d_ws;
    u16* qkvwh = (u16*)(ws);                  // 3,538,944   [presplit .. gemm_qkv]
    u16* qkvwl = (u16*)(ws + 3538944);        // 3,538,944
    u16* xh    = (u16*)(ws + 7077888);        // 6,291,456   [presplit .. gemm_qkv]
    u16* xl    = (u16*)(ws + 13369344);       // 6,291,456
    u16* qh    = (u16*)(ws + 19660800);       // 6,291,456
    u16* ql    = (u16*)(ws + 25952256);
    u16* kh    = (u16*)(ws + 32243712);
    u16* kl    = (u16*)(ws + 38535168);
    u16* vT    = (u16*)(ws + 44826624);       // -> 51,118,080
    u16* ao    = (u16*)(ws + 7077888);        // aliases xh (dead after gemm_qkv)
    u16* pwh   = (u16*)(ws + 13369344);       // aliases xl (split after gemm_qkv)
    u16* pwl   = (u16*)(ws + 14548992);

    // 1) presplit x and qkv_w   (x: 4096*768 floats = 786,432 float4)
    presplit<<<dim3(3072), 256, 0, stream>>>(x, xh, xl, 786432);
    presplit<<<dim3(1728), 256, 0, stream>>>(qkv_w, qkvwh, qkvwl, 442368);

    // 2) QKV projection (single-buffer m97 structure, 128x64 tiles, 1152 blocks)
    gemm_qkv<<<dim3(1152), 256, 0, stream>>>(xh, xl, qkvwh, qkvwl, qh, ql, kh, kl, vT);

    // 3) presplit proj_w (into xl's region, now dead)
    presplit<<<dim3(576), 256, 0, stream>>>(proj_w, pwh, pwl, 147456);

    // 4) attention -> attout bf16 (768 blocks, 16 rows/wave, V reg-prefetch)
    attn_mfma<<<dim3(768), 256, 0, stream>>>(qh, ql, kh, kl, vT, rel_table, ao);

    // 5) output projection + bias -> f32 (single-buffer, 768 blocks)
    gemm_proj<<<dim3(768), 256, 0, stream>>>(ao, pwh, pwl, proj_b, (float*)d_out);
}